// Round 17
// baseline (135.926 us; speedup 1.0000x reference)
//
#include <hip/hip_runtime.h>
#include <cstddef>
#include <cstdint>

// Problem constants (bs=32, L=128, d=512, E=16)
#define BS 32
#define LL 128
#define DD 512
#define EE 16
#define EPSF 1e-9f
#define INV_SQRT_D 0.04419417382415922f  // 1/sqrt(512)

typedef short bf16x8 __attribute__((ext_vector_type(8)));
typedef float f32x4 __attribute__((ext_vector_type(4)));

__device__ __forceinline__ float sigmoidf_(float x) {
  return 1.f / (1.f + __expf(-x));
}
__device__ __forceinline__ unsigned short f2bf(float f) {  // RNE
  union { float f; unsigned u; } v; v.f = f;
  unsigned r = v.u + 0x7fffu + ((v.u >> 16) & 1u);
  return (unsigned short)(r >> 16);
}
__device__ __forceinline__ float bf2f(unsigned short h) {
  union { unsigned u; float f; } v; v.u = ((unsigned)h) << 16; return v.f;
}

// Swizzle scheme for [R][32-ushort] LDS tiles (64B rows):
// staging source quad = (lane&3)^((lane>>3)&3); read quad = ((lane>>4)^((lane>>1)&3)).
// Verified r8: SQ_LDS_BANK_CONFLICT 3.9M -> 0.

// ---------------------------------------------------------------------------
// K0: fp32 -> bf16 staging. x: hi only (r15-validated, absmax 0.0431).
// Weights: split hi+lo (precision-critical factor).
// ---------------------------------------------------------------------------
__global__ __launch_bounds__(256) void cvt_split(
    const float* __restrict__ x,
    const float* __restrict__ w0, const float* __restrict__ w1,
    const float* __restrict__ w2, const float* __restrict__ w3,
    const float* __restrict__ w4, const float* __restrict__ w5,
    const float* __restrict__ w6,
    unsigned short* __restrict__ xh,
    unsigned short* __restrict__ wh, unsigned short* __restrict__ wl)
{
  const int q = blockIdx.x * 256 + threadIdx.x;   // quad index
  if (q >= 983040) return;
  if (q < 524288) {
    const float4 v = *(const float4*)(x + (size_t)q * 4);
    ushort4 h;
    h.x = f2bf(v.x); h.y = f2bf(v.y); h.z = f2bf(v.z); h.w = f2bf(v.w);
    *(ushort4*)(xh + (size_t)q * 4) = h;
    return;
  }
  const int qq = q - 524288;
  const int seg = qq >> 16;
  const int off = (qq & 65535) * 4;
  const float* p;
  if      (seg == 0) p = w0; else if (seg == 1) p = w1;
  else if (seg == 2) p = w2; else if (seg == 3) p = w3;
  else if (seg == 4) p = w4; else if (seg == 5) p = w5;
  else               p = w6;
  const float4 v = *(const float4*)(p + off);
  ushort4 h, l;
  h.x = f2bf(v.x); l.x = f2bf(v.x - bf2f(h.x));
  h.y = f2bf(v.y); l.y = f2bf(v.y - bf2f(h.y));
  h.z = f2bf(v.z); l.z = f2bf(v.z - bf2f(h.z));
  h.w = f2bf(v.w); l.w = f2bf(v.w - bf2f(h.w));
  *(ushort4*)(wh + (size_t)qq * 4) = h;
  *(ushort4*)(wl + (size_t)qq * 4) = l;
}

// ---------------------------------------------------------------------------
// K1: fused 5-way MFMA linear over x (validated r15/r16): N=2560.
// ---------------------------------------------------------------------------
__global__ __launch_bounds__(256) void linA_fused(
    const unsigned short* __restrict__ xh,
    const unsigned short* __restrict__ wh, const unsigned short* __restrict__ wl,
    const float* __restrict__ b0, const float* __restrict__ b1,
    const float* __restrict__ b2, const float* __restrict__ b3,
    const float* __restrict__ b4,
    unsigned short* __restrict__ condh, unsigned short* __restrict__ condl,
    unsigned short* __restrict__ xkeyh, unsigned short* __restrict__ xkeyl,
    unsigned short* __restrict__ tmpah, unsigned short* __restrict__ tmpbh,
    unsigned short* __restrict__ selb)
{
  __shared__ __align__(16) char smem[32768];   // 2 x 16KB buffers
  const int tid = threadIdx.x;
  const int wv = tid >> 6, lane = tid & 63;
  const int m0 = blockIdx.x * 128;
  const int nglob0 = blockIdx.y * 64;
  const int seg = nglob0 >> 9;               // 0..4
  const int n0 = nglob0 & 511;
  const unsigned short* Wh = wh + (size_t)seg * 262144;
  const unsigned short* Wl = wl + (size_t)seg * 262144;
  const float* bias = (seg == 0) ? b0 : (seg == 1) ? b1 : (seg == 2) ? b2
                      : (seg == 3) ? b3 : b4;
  const int wm = (wv >> 1) * 64, wn = (wv & 1) * 32;
  const int sr4 = lane >> 2;
  const int scol = ((lane & 3) ^ ((lane >> 3) & 3)) * 8;
  const int fr = lane & 15;
  const int fk = (((lane >> 4) ^ ((lane >> 1) & 3))) * 8;

  auto stage = [&](int d, int k0) {
    char* base = smem + d * 16384;
    unsigned short* AsH = (unsigned short*)base;            // 8KB (128x32)
    unsigned short* BsH = (unsigned short*)(base + 8192);   // 4KB (64x32)
    unsigned short* BsL = (unsigned short*)(base + 12288);  // 4KB
#pragma unroll
    for (int c = 0; c < 2; ++c) {
      const size_t ga = (size_t)(m0 + wv * 32 + c * 16 + sr4) * 512 + k0 + scol;
      __builtin_amdgcn_global_load_lds(
          (const __attribute__((address_space(1))) unsigned int*)(xh + ga),
          (__attribute__((address_space(3))) unsigned int*)(AsH + wv * 1024 + c * 512),
          16, 0, 0);
    }
    {
      const size_t gb = (size_t)(n0 + wv * 16 + sr4) * 512 + k0 + scol;
      __builtin_amdgcn_global_load_lds(
          (const __attribute__((address_space(1))) unsigned int*)(Wh + gb),
          (__attribute__((address_space(3))) unsigned int*)(BsH + wv * 512),
          16, 0, 0);
      __builtin_amdgcn_global_load_lds(
          (const __attribute__((address_space(1))) unsigned int*)(Wl + gb),
          (__attribute__((address_space(3))) unsigned int*)(BsL + wv * 512),
          16, 0, 0);
    }
  };

  f32x4 acc[4][2] = {};
  stage(0, 0);
  __syncthreads();
  for (int k0 = 0; k0 < 512; k0 += 32) {
    const int cur = (k0 >> 5) & 1;
    if (k0 + 32 < 512) stage(cur ^ 1, k0 + 32);
    char* base = smem + cur * 16384;
    unsigned short* AsH = (unsigned short*)base;
    unsigned short* BsH = (unsigned short*)(base + 8192);
    unsigned short* BsL = (unsigned short*)(base + 12288);
    bf16x8 ah[4], bh[2], bl[2];
#pragma unroll
    for (int i = 0; i < 4; ++i)
      ah[i] = *(const bf16x8*)&AsH[(wm + 16 * i + fr) * 32 + fk];
#pragma unroll
    for (int j = 0; j < 2; ++j) {
      bh[j] = *(const bf16x8*)&BsH[(wn + 16 * j + fr) * 32 + fk];
      bl[j] = *(const bf16x8*)&BsL[(wn + 16 * j + fr) * 32 + fk];
    }
    __builtin_amdgcn_s_setprio(1);
#pragma unroll
    for (int i = 0; i < 4; ++i)
#pragma unroll
      for (int j = 0; j < 2; ++j) {
        acc[i][j] = __builtin_amdgcn_mfma_f32_16x16x32_bf16(ah[i], bh[j], acc[i][j], 0, 0, 0);
        acc[i][j] = __builtin_amdgcn_mfma_f32_16x16x32_bf16(ah[i], bl[j], acc[i][j], 0, 0, 0);
      }
    __builtin_amdgcn_s_setprio(0);
    __syncthreads();
  }
  // ---- vectorized epilogue via LDS transpose (2 passes of 64 rows) ----
  const int fq4 = (lane >> 4) * 4;
  float (*Epi)[68] = (float(*)[68])smem;
  const int ep_row = tid >> 2;          // 0..63
  const int ep_c0 = (tid & 3) * 16;     // 0,16,32,48
  for (int pass = 0; pass < 2; ++pass) {
    __syncthreads();
    if ((wv >> 1) == pass) {
#pragma unroll
      for (int j = 0; j < 2; ++j)
#pragma unroll
        for (int i = 0; i < 4; ++i)
#pragma unroll
          for (int q = 0; q < 4; ++q)
            Epi[16 * i + fq4 + q][wn + 16 * j + fr] = acc[i][j][q];
    }
    __syncthreads();
    const int m = m0 + pass * 64 + ep_row;
    const int nb = n0 + ep_c0;
    float vv[16];
#pragma unroll
    for (int t = 0; t < 4; ++t) {
      const float4 e = *(const float4*)&Epi[ep_row][ep_c0 + 4 * t];
      const float4 bv = *(const float4*)(bias + nb + 4 * t);
      vv[4 * t + 0] = e.x + bv.x; vv[4 * t + 1] = e.y + bv.y;
      vv[4 * t + 2] = e.z + bv.z; vv[4 * t + 3] = e.w + bv.w;
    }
    const size_t o = (size_t)m * 512 + nb;
    if (seg <= 1) {
      unsigned hu[8], lu[8];
#pragma unroll
      for (int t = 0; t < 8; ++t) {
        const float v0 = vv[2 * t], v1 = vv[2 * t + 1];
        const unsigned short h0 = f2bf(v0), h1 = f2bf(v1);
        hu[t] = (unsigned)h0 | ((unsigned)h1 << 16);
        lu[t] = (unsigned)f2bf(v0 - bf2f(h0)) | ((unsigned)f2bf(v1 - bf2f(h1)) << 16);
      }
      unsigned short* oh = seg ? xkeyh : condh;
      unsigned short* ol = seg ? xkeyl : condl;
      uint4 H0, H1, L0, L1;
      H0.x = hu[0]; H0.y = hu[1]; H0.z = hu[2]; H0.w = hu[3];
      H1.x = hu[4]; H1.y = hu[5]; H1.z = hu[6]; H1.w = hu[7];
      L0.x = lu[0]; L0.y = lu[1]; L0.z = lu[2]; L0.w = lu[3];
      L1.x = lu[4]; L1.y = lu[5]; L1.z = lu[6]; L1.w = lu[7];
      *(uint4*)(oh + o) = H0; *(uint4*)(oh + o + 8) = H1;
      *(uint4*)(ol + o) = L0; *(uint4*)(ol + o + 8) = L1;
    } else if (seg <= 3) {
      unsigned hu[8];
#pragma unroll
      for (int t = 0; t < 8; ++t)
        hu[t] = (unsigned)f2bf(vv[2 * t]) | ((unsigned)f2bf(vv[2 * t + 1]) << 16);
      unsigned short* oh = (seg == 2) ? tmpah : tmpbh;
      uint4 H0, H1;
      H0.x = hu[0]; H0.y = hu[1]; H0.z = hu[2]; H0.w = hu[3];
      H1.x = hu[4]; H1.y = hu[5]; H1.z = hu[6]; H1.w = hu[7];
      *(uint4*)(oh + o) = H0; *(uint4*)(oh + o + 8) = H1;
    } else {
      unsigned hu[8];
#pragma unroll
      for (int t = 0; t < 8; ++t)
        hu[t] = (unsigned)f2bf(sigmoidf_(vv[2 * t]))
              | ((unsigned)f2bf(sigmoidf_(vv[2 * t + 1])) << 16);
      uint4 H0, H1;
      H0.x = hu[0]; H0.y = hu[1]; H0.z = hu[2]; H0.w = hu[3];
      H1.x = hu[4]; H1.y = hu[5]; H1.z = hu[6]; H1.w = hu[7];
      *(uint4*)(selb + o) = H0; *(uint4*)(selb + o + 8) = H1;
    }
  }
}

// ---------------------------------------------------------------------------
// K2: MERGED mid-stage (validated r16): blocks 0..287 = qtck, 288..799 = linB.
// ---------------------------------------------------------------------------
__global__ __launch_bounds__(256) void mid_fused(
    const float* __restrict__ qtab,
    const unsigned short* __restrict__ condh, const unsigned short* __restrict__ condl,
    const unsigned short* __restrict__ xkeyh, const unsigned short* __restrict__ xkeyl,
    float* __restrict__ ZR,
    const unsigned short* __restrict__ tmpah, const unsigned short* __restrict__ tmpbh,
    const unsigned short* __restrict__ wh, const unsigned short* __restrict__ wl,
    const float* __restrict__ bca1, const float* __restrict__ bcb1,
    unsigned short* __restrict__ cab, unsigned short* __restrict__ cbb)
{
  __shared__ __align__(16) char smem[32768];
  const int tid = threadIdx.x;
  const int wv = tid >> 6, lane = tid & 63;
  const int sr4 = lane >> 2;
  const int scol = ((lane & 3) ^ ((lane >> 3) & 3)) * 8;
  const int fr = lane & 15;
  const int fk = (((lane >> 4) ^ ((lane >> 1) & 3))) * 8;

  if (blockIdx.x < 288) {
    // ================= qtck path =================
    unsigned short* Ahs = (unsigned short*)smem;             // 2KB (16x32)
    unsigned short* Als = (unsigned short*)(smem + 2048);    // 2KB
    unsigned short* Bhs = (unsigned short*)(smem + 4096);    // 8KB (128x32)
    unsigned short* Bls = (unsigned short*)(smem + 12288);   // 8KB
    const int blk = blockIdx.x;
    const int b = blk / 9, mi = blk % 9;
    const unsigned short* Asrch = condh + ((size_t)b * 128 + (mi - 1) * 16) * 512;
    const unsigned short* Asrcl = condl + ((size_t)b * 128 + (mi - 1) * 16) * 512;
    f32x4 acc[2] = {};
    for (int k0 = 0; k0 < 512; k0 += 32) {
      __syncthreads();
      if (mi == 0) {
        const int idx = tid * 2;
        const int row = idx >> 5, col = idx & 31;
        const float2 v = *(const float2*)(qtab + (size_t)row * 512 + k0 + col);
        const int pos = row * 32 + (((col >> 3) ^ ((row >> 1) & 3)) * 8) + (col & 7);
        const unsigned short h0 = f2bf(v.x), h1 = f2bf(v.y);
        ushort2 hh, ll;
        hh.x = h0; hh.y = h1;
        ll.x = f2bf(v.x - bf2f(h0)); ll.y = f2bf(v.y - bf2f(h1));
        *(ushort2*)&Ahs[pos] = hh;
        *(ushort2*)&Als[pos] = ll;
      } else {
        if (wv == 0) {
          const size_t ga = (size_t)sr4 * 512 + k0 + scol;
          __builtin_amdgcn_global_load_lds(
              (const __attribute__((address_space(1))) unsigned int*)(Asrch + ga),
              (__attribute__((address_space(3))) unsigned int*)Ahs, 16, 0, 0);
        } else if (wv == 1) {
          const size_t ga = (size_t)sr4 * 512 + k0 + scol;
          __builtin_amdgcn_global_load_lds(
              (const __attribute__((address_space(1))) unsigned int*)(Asrcl + ga),
              (__attribute__((address_space(3))) unsigned int*)Als, 16, 0, 0);
        }
      }
#pragma unroll
      for (int t = 0; t < 2; ++t) {
        const int issue = wv * 2 + t;
        const size_t gb = ((size_t)b * 128 + issue * 16 + sr4) * 512 + k0 + scol;
        __builtin_amdgcn_global_load_lds(
            (const __attribute__((address_space(1))) unsigned int*)(xkeyh + gb),
            (__attribute__((address_space(3))) unsigned int*)(Bhs + issue * 512),
            16, 0, 0);
        __builtin_amdgcn_global_load_lds(
            (const __attribute__((address_space(1))) unsigned int*)(xkeyl + gb),
            (__attribute__((address_space(3))) unsigned int*)(Bls + issue * 512),
            16, 0, 0);
      }
      __syncthreads();
      const bf16x8 ah = *(const bf16x8*)&Ahs[fr * 32 + fk];
      const bf16x8 al = *(const bf16x8*)&Als[fr * 32 + fk];
      __builtin_amdgcn_s_setprio(1);
#pragma unroll
      for (int j = 0; j < 2; ++j) {
        const int nf = wv * 2 + j;
        const bf16x8 bh = *(const bf16x8*)&Bhs[(16 * nf + fr) * 32 + fk];
        const bf16x8 bl = *(const bf16x8*)&Bls[(16 * nf + fr) * 32 + fk];
        acc[j] = __builtin_amdgcn_mfma_f32_16x16x32_bf16(ah, bh, acc[j], 0, 0, 0);
        acc[j] = __builtin_amdgcn_mfma_f32_16x16x32_bf16(ah, bl, acc[j], 0, 0, 0);
        acc[j] = __builtin_amdgcn_mfma_f32_16x16x32_bf16(al, bh, acc[j], 0, 0, 0);
      }
      __builtin_amdgcn_s_setprio(0);
    }
    const int fq4 = (lane >> 4) * 4;
#pragma unroll
    for (int j = 0; j < 2; ++j) {
      const int n = 16 * (wv * 2 + j) + fr;
#pragma unroll
      for (int q = 0; q < 4; ++q) {
        const int m = mi * 16 + fq4 + q;
        ZR[((size_t)b * 144 + m) * 128 + n] = acc[j][q] * INV_SQRT_D;
      }
    }
    return;
  }

  // ================= linB path =================
  const int idx = blockIdx.x - 288;       // 0..511
  const int m0 = (idx & 31) * 128;
  const int by = idx >> 5;                // 0..15
  const int seg = by >> 3;
  const int n0 = (by & 7) * 64;
  const unsigned short* Ah = seg ? tmpbh : tmpah;
  const unsigned short* Wh = wh + (size_t)(5 + seg) * 262144;
  const unsigned short* Wl = wl + (size_t)(5 + seg) * 262144;
  const float* bias = seg ? bcb1 : bca1;
  unsigned short* out = seg ? cbb : cab;
  const int wm = (wv >> 1) * 64, wn = (wv & 1) * 32;

  auto stage = [&](int d, int k0) {
    char* base = smem + d * 16384;
    unsigned short* AsH = (unsigned short*)base;
    unsigned short* BsH = (unsigned short*)(base + 8192);
    unsigned short* BsL = (unsigned short*)(base + 12288);
#pragma unroll
    for (int c = 0; c < 2; ++c) {
      const size_t ga = (size_t)(m0 + wv * 32 + c * 16 + sr4) * 512 + k0 + scol;
      __builtin_amdgcn_global_load_lds(
          (const __attribute__((address_space(1))) unsigned int*)(Ah + ga),
          (__attribute__((address_space(3))) unsigned int*)(AsH + wv * 1024 + c * 512),
          16, 0, 0);
    }
    {
      const size_t gb = (size_t)(n0 + wv * 16 + sr4) * 512 + k0 + scol;
      __builtin_amdgcn_global_load_lds(
          (const __attribute__((address_space(1))) unsigned int*)(Wh + gb),
          (__attribute__((address_space(3))) unsigned int*)(BsH + wv * 512),
          16, 0, 0);
      __builtin_amdgcn_global_load_lds(
          (const __attribute__((address_space(1))) unsigned int*)(Wl + gb),
          (__attribute__((address_space(3))) unsigned int*)(BsL + wv * 512),
          16, 0, 0);
    }
  };

  f32x4 acc[4][2] = {};
  stage(0, 0);
  __syncthreads();
  for (int k0 = 0; k0 < 512; k0 += 32) {
    const int cur = (k0 >> 5) & 1;
    if (k0 + 32 < 512) stage(cur ^ 1, k0 + 32);
    char* base = smem + cur * 16384;
    unsigned short* AsH = (unsigned short*)base;
    unsigned short* BsH = (unsigned short*)(base + 8192);
    unsigned short* BsL = (unsigned short*)(base + 12288);
    bf16x8 ah[4], bh[2], bl[2];
#pragma unroll
    for (int i = 0; i < 4; ++i)
      ah[i] = *(const bf16x8*)&AsH[(wm + 16 * i + fr) * 32 + fk];
#pragma unroll
    for (int j = 0; j < 2; ++j) {
      bh[j] = *(const bf16x8*)&BsH[(wn + 16 * j + fr) * 32 + fk];
      bl[j] = *(const bf16x8*)&BsL[(wn + 16 * j + fr) * 32 + fk];
    }
    __builtin_amdgcn_s_setprio(1);
#pragma unroll
    for (int i = 0; i < 4; ++i)
#pragma unroll
      for (int j = 0; j < 2; ++j) {
        acc[i][j] = __builtin_amdgcn_mfma_f32_16x16x32_bf16(ah[i], bh[j], acc[i][j], 0, 0, 0);
        acc[i][j] = __builtin_amdgcn_mfma_f32_16x16x32_bf16(ah[i], bl[j], acc[i][j], 0, 0, 0);
      }
    __builtin_amdgcn_s_setprio(0);
    __syncthreads();
  }
  const int fq4 = (lane >> 4) * 4;
  float (*Epi)[68] = (float(*)[68])smem;
  const int ep_row = tid >> 2;
  const int ep_c0 = (tid & 3) * 16;
  for (int pass = 0; pass < 2; ++pass) {
    __syncthreads();
    if ((wv >> 1) == pass) {
#pragma unroll
      for (int j = 0; j < 2; ++j)
#pragma unroll
        for (int i = 0; i < 4; ++i)
#pragma unroll
          for (int q = 0; q < 4; ++q)
            Epi[16 * i + fq4 + q][wn + 16 * j + fr] = acc[i][j][q];
    }
    __syncthreads();
    const int m = m0 + pass * 64 + ep_row;
    const int nb = n0 + ep_c0;
    const size_t o = (size_t)m * 512 + nb;
    float vv[16];
#pragma unroll
    for (int t = 0; t < 4; ++t) {
      const float4 e = *(const float4*)&Epi[ep_row][ep_c0 + 4 * t];
      const float4 bv = *(const float4*)(bias + nb + 4 * t);
      vv[4 * t + 0] = e.x + bv.x; vv[4 * t + 1] = e.y + bv.y;
      vv[4 * t + 2] = e.z + bv.z; vv[4 * t + 3] = e.w + bv.w;
    }
    const uint4 G0 = *(const uint4*)(Ah + o);
    const uint4 G1 = *(const uint4*)(Ah + o + 8);
    const unsigned gw[8] = {G0.x, G0.y, G0.z, G0.w, G1.x, G1.y, G1.z, G1.w};
    unsigned hu[8];
#pragma unroll
    for (int t = 0; t < 8; ++t) {
      const float g0 = bf2f((unsigned short)(gw[t] & 0xffff));
      const float g1 = bf2f((unsigned short)(gw[t] >> 16));
      hu[t] = (unsigned)f2bf(g0 * sigmoidf_(vv[2 * t]))
            | ((unsigned)f2bf(g1 * sigmoidf_(vv[2 * t + 1])) << 16);
    }
    uint4 H0, H1;
    H0.x = hu[0]; H0.y = hu[1]; H0.z = hu[2]; H0.w = hu[3];
    H1.x = hu[4]; H1.y = hu[5]; H1.z = hu[6]; H1.w = hu[7];
    *(uint4*)(out + o) = H0; *(uint4*)(out + o + 8) = H1;
  }
}

// ---------------------------------------------------------------------------
// K4: fused forward + backward sums (validated r12-r16).
// ---------------------------------------------------------------------------
__global__ __launch_bounds__(256) void sums_fused(
    const float* __restrict__ ZR,
    float* __restrict__ inv_fw_a, float* __restrict__ inv_fw_b,
    float* __restrict__ invS_bw_a, float* __restrict__ invS_bw_b,
    float* __restrict__ sbq2_a, float* __restrict__ sbq2_b,
    float* __restrict__ sbe2_a, float* __restrict__ sbe2_b)
{
  __shared__ float se_a[2][16][129];
  __shared__ float se_b[2][16][129];
  __shared__ float red_a[2][128], red_b[2][128];
  const int blk = blockIdx.x;
  if (blk < 256) {
    const int idx = blk * 256 + threadIdx.x;   // b*2048+n
    const int b = idx >> 11, n = idx & 2047;
    const int lq = n >> 4, e = n & 15;
    const float* qrow = ZR + ((size_t)b * 144 + e) * LL;
    const float* crow = ZR + ((size_t)b * 144 + 16 + lq) * LL;
    float sa = 0.f, sb = 0.f;
    const int kend = lq + 1;
    int k = 0;
    for (; k + 4 <= kend; k += 4) {
      const float4 qv = *(const float4*)(qrow + k);
      const float4 cv = *(const float4*)(crow + k);
      float v;
      v = qv.x + cv.x; sa += fmaxf(v, 0.f); sb += fmaxf(-v, 0.f);
      v = qv.y + cv.y; sa += fmaxf(v, 0.f); sb += fmaxf(-v, 0.f);
      v = qv.z + cv.z; sa += fmaxf(v, 0.f); sb += fmaxf(-v, 0.f);
      v = qv.w + cv.w; sa += fmaxf(v, 0.f); sb += fmaxf(-v, 0.f);
    }
    for (; k < kend; ++k) {
      const float v = qrow[k] + crow[k];
      sa += fmaxf(v, 0.f);
      sb += fmaxf(-v, 0.f);
    }
    inv_fw_a[idx] = 1.f / (sa + EPSF);
    inv_fw_b[idx] = 1.f / (sb + EPSF);
    return;
  }
  // ---- backward part: bidx = (blk-256)*2 + half ----
  const int half = threadIdx.x >> 7;   // 0/1
  const int t = threadIdx.x & 127;     // l_q
  const int bidx = (blk - 256) * 2 + half;   // b*128 + l
  const int b = bidx >> 7, l = bidx & 127;
  const float* zb = ZR + (size_t)b * 144 * LL;
  float qa = 0.f, qb = 0.f;
  const float ckl = zb[(16 + t) * LL + l];
  if (t <= l) {
#pragma unroll
    for (int e = 0; e < 16; ++e) {
      const float v = zb[e * LL + l] + ckl;
      const float pa = fmaxf(v, 0.f), pb = fmaxf(-v, 0.f);
      se_a[half][e][t] = pa; se_b[half][e][t] = pb;
      qa += pa; qb += pb;
    }
  } else {
#pragma unroll
    for (int e = 0; e < 16; ++e) { se_a[half][e][t] = 0.f; se_b[half][e][t] = 0.f; }
  }
  red_a[half][t] = qa; red_b[half][t] = qb;
  __syncthreads();
  for (int off = 64; off >= 1; off >>= 1) {
    if (t < off) {
      red_a[half][t] += red_a[half][t + off];
      red_b[half][t] += red_b[half][t + off];
    }
    __syncthreads();
  }
  const float inv_a = 1.f / (red_a[half][0] + EPSF);
  const float inv_b = 1.f / (red_b[half][0] + EPSF);
  if (t == 0) { invS_bw_a[bidx] = inv_a; invS_bw_b[bidx] = inv_b; }
  sbq2_a[(size_t)bidx * LL + t] = qa * (2.f * inv_a);
  sbq2_b[(size_t)bidx * LL + t] = qb * (2.f * inv_b);
  if (t < 16) {
    float sa = 0.f, sb = 0.f;
    for (int i = 0; i < 128; ++i) { sa += se_a[half][t][i]; sb += se_b[half][t][i]; }
    sbe2_a[(size_t)bidx * EE + t] = sa * (2.f * inv_a);
    sbe2_b[(size_t)bidx * EE + t] = sb * (2.f * inv_b);
  }
}

// ---------------------------------------------------------------------------
// K6: fused masked-operand generation + bf16 MFMA, swizzled V/U tiles.
// NOW 16 subparts/b (16-lq chunks), 512 blocks = 2/CU, 8 iterations each.
// Wpart slot = s directly: tile0 -> s 0..3, tile1 -> s 4..11, tile2 -> s 12..15.
// ---------------------------------------------------------------------------
__global__ __launch_bounds__(256) void wmat_mfma(
    const float* __restrict__ ZR,
    const float* __restrict__ inv_fw_a, const float* __restrict__ inv_fw_b,
    const float* __restrict__ invS_bw_a, const float* __restrict__ invS_bw_b,
    float* __restrict__ Wpa, float* __restrict__ Wpb)
{
  __shared__ float QTs[16][128];
  __shared__ float CKs[16][128];
  __shared__ float IFa[256], IFb[256];
  __shared__ unsigned short VAt[64][32], VBt[64][32];
  __shared__ unsigned short UAt[64][32], UBt[64][32];
  const int blk = blockIdx.x;          // b*16 + s
  const int b = blk >> 4, s = blk & 15;
  int t, p;
  if (s < 4)       { t = 0; p = s; }
  else if (s < 12) { t = 1; p = s - 4; }
  else             { t = 2; p = s - 12; }
  const int l0 = (t > 0) ? 64 : 0;
  const int k0 = (t == 2) ? 64 : 0;
  const int lqb = ((t == 2) ? 64 : 0) + p * 16;
  const int tid = threadIdx.x, wv = tid >> 6, lane = tid & 63;
  const float* zb = ZR + (size_t)b * 144 * LL;
#pragma unroll
  for (int i = 0; i < 2; ++i) {
    const int o = (tid * 2 + i) * 4;
    *(float4*)((float*)QTs + o) = *(const float4*)(zb + o);
  }
  const float* cksrc = zb + (size_t)(16 + lqb) * LL;
  {
    const int o = tid * 8;
    *(float4*)((float*)CKs + o)     = *(const float4*)(cksrc + o);
    *(float4*)((float*)CKs + o + 4) = *(const float4*)(cksrc + o + 4);
  }
  {
    IFa[tid] = inv_fw_a[(size_t)b * 2048 + lqb * 16 + tid];
    IFb[tid] = inv_fw_b[(size_t)b * 2048 + lqb * 16 + tid];
  }
  const int gr = tid >> 2;
  const int nsub = (tid & 3) * 8;
  const int nsubs = ((tid & 3) ^ ((tid >> 3) & 3)) * 8;
  const int e0 = nsub & 15;
  const int lqo = nsub >> 4;
  const int fr = lane & 15;
  const int fk = (((lane >> 4) ^ ((lane >> 1) & 3))) * 8;
  const int lc = l0 + gr, kc = k0 + gr;
  const bool same_col = (l0 == k0);
  f32x4 aa[4] = {}, ab[4] = {};
  for (int it = 0; it < 8; ++it) {
    __syncthreads();
    const int lql = it * 2 + lqo;          // 0..15
    const int lqg = lqb + lql;
    const float ckv = CKs[lql][lc];
    const float cku = same_col ? ckv : CKs[lql][kc];
    const bool mv = (lqg <= lc);
    const bool mu = (kc <= lqg);
    unsigned short va[8], vb[8], ua[8], ub[8];
#pragma unroll
    for (int i = 0; i < 8; ++i) {
      const float zq = QTs[e0 + i][lc];
      const float z = zq + ckv;
      va[i] = f2bf(mv ? fmaxf(z, 0.f) : 0.f);
      vb[i] = f2bf(mv ? fmaxf(-z, 0.f) : 0.f);
      const float zq2 = same_col ? zq : QTs[e0 + i][kc];
      const float z2 = zq2 + cku;
      const float ia = IFa[lql * 16 + e0 + i];
      const float ib = IFb[lql * 16 + e0 + i];
      ua[i] = f2bf(mu ? fmaxf(z2, 0.f) * ia : 0.f);
      ub[i] = f2bf(mu ? fmaxf(-z2, 0.f) * ib : 0.f);
    }
    ushort4 w0, w1;
    w0.x = va[0]; w0.y = va[1]; w0.z = va[2]; w0.w = va[3];
    w1.x = va[4]; w1.y = va[5]; w1.z = va[6]; w1.w = va[7];
    *(ushort4*)&VAt[gr][nsubs] = w0; *(ushort4*)&VAt[gr][nsubs + 4] = w1;
    w0.x = vb[0]; w0.y = vb[1]; w0.z = vb[2]; w0.w = vb[3];
    w1.x = vb[4]; w1.y = vb[5]; w1.z = vb[6]; w1.w = vb[7];
    *(ushort4*)&VBt[gr][nsubs] = w0; *(ushort4*)&VBt[gr][nsubs + 4] = w1;
    w0.x = ua[0]; w0.y = ua[1]; w0.z = ua[2]; w0.w = ua[3];
    w1.x = ua[4]; w1.y = ua[5]; w1.z = ua[6]; w1.w = ua[7];
    *(ushort4*)&UAt[gr][nsubs] = w0; *(ushort4*)&UAt[gr][nsubs + 4] = w1;
    w0.x = ub[0]; w0.y = ub[1]; w0.z = ub[2]; w0.w = ub[3];
    w1.x = ub[4]; w1.y = ub[5]; w1.z = ub[6]; w1.w = ub[7];
    *(ushort4*)&UBt[gr][nsubs] = w0; *(ushort4*)&UBt[gr][nsubs + 4] = w1;
    __syncthreads();
    const bf16x8 afa = *(const bf16x8*)&VAt[16 * wv + fr][fk];
    const bf16x8 afb = *(const bf16x8*)&VBt[16 * wv + fr][fk];
    __builtin_amdgcn_s_setprio(1);
#pragma unroll
    for (int c = 0; c < 4; ++c) {
      const bf16x8 bfa = *(const bf16x8*)&UAt[16 * c + fr][fk];
      const bf16x8 bfb = *(const bf16x8*)&UBt[16 * c + fr][fk];
      aa[c] = __builtin_amdgcn_mfma_f32_16x16x32_bf16(afa, bfa, aa[c], 0, 0, 0);
      ab[c] = __builtin_amdgcn_mfma_f32_16x16x32_bf16(afb, bfb, ab[c], 0, 0, 0);
    }
    __builtin_amdgcn_s_setprio(0);
  }
  const int llb = 16 * wv + (lane >> 4) * 4;
#pragma unroll
  for (int c = 0; c < 4; ++c) {
    const int kl = 16 * c + fr;
#pragma unroll
    for (int q = 0; q < 4; ++q) {
      const int llo = llb + q;
      const int lg = l0 + llo;
      const float sa = invS_bw_a[b * LL + lg];
      const float sb = invS_bw_b[b * LL + lg];
      const size_t base = ((size_t)(b * 16 + s)) * 4096 + (size_t)llo * 64 + kl;
      Wpa[base] = aa[c][q] * sa;
      Wpb[base] = ab[c][q] * sb;
    }
  }
}

// ---------------------------------------------------------------------------
// K7: final contraction as bf16 MFMA, K=416. A-stage partial sums updated for
// 16-slot Wp layout: tile0 = slots 0..3 (4 partials), tile1 = 4..11 (8),
// tile2 = 12..15 (4).
// ---------------------------------------------------------------------------
__global__ __launch_bounds__(256) void final_mfma(
    const float* __restrict__ Wpa, const float* __restrict__ Wpb,
    const float* __restrict__ sbq2_a, const float* __restrict__ sbq2_b,
    const float* __restrict__ sbe2_a, const float* __restrict__ sbe2_b,
    const unsigned short* __restrict__ cab, const unsigned short* __restrict__ cbb,
    const unsigned short* __restrict__ condh, const unsigned short* __restrict__ condl,
    const float* __restrict__ btab,
    const unsigned short* __restrict__ selb, float* __restrict__ out)
{
  __shared__ unsigned short Aa[64][40], Ab[64][40];
  __shared__ unsigned short Ba[128][40], Bb[128][40];
  const int b = blockIdx.x, ls = blockIdx.y, ds = blockIdx.z;
  const int l0 = ls * 64, d0 = ds * 128;
  const int tid = threadIdx.x, wv = tid >> 6, lane = tid & 63;
  const int fr = lane & 15, fk = (lane >> 4) * 8;
  const int dl0 = wv * 32;
  const int al = tid & 63, akb = tid >> 6;
  const int bkl = tid >> 3, bdb = (tid & 7) * 16;
  f32x4 acc[4][2][2] = {};
  for (int st = 0; st < 13; ++st) {
    const int k0 = st * 32;
    __syncthreads();
    {
      float va[8] = {}, vb[8] = {};
      const int kq8 = akb * 8;
      if (st < 4) {
        int nparts = 0; size_t base = 0;
        if (st < 2) {
          if (ls == 0) { nparts = 4; base = ((size_t)(b * 16 + 0)) * 4096 + (size_t)al * 64 + st * 32 + kq8; }
          else         { nparts = 8; base = ((size_t)(b * 16 + 4)) * 4096 + (size_t)al * 64 + st * 32 + kq8; }
        } else {
          if (ls == 1) { nparts = 4; base = ((size_t)(b * 16 + 12)) * 4096 + (size_t)al * 64 + (st - 2) * 32 + kq8; }
        }
        if (nparts) {
#pragma unroll
          for (int h = 0; h < 2; ++h) {
            float ra0 = 0.f, ra1 = 0.f, ra2 = 0.f, ra3 = 0.f;
            float rb0 = 0.f, rb1 = 0.f, rb2 = 0.f, rb3 = 0.f;
            for (int pp = 0; pp < nparts; ++pp) {
              const float4 pA = *(const float4*)(Wpa + base + (size_t)pp * 4096 + h * 4);
              ra0 += pA.x; ra1 += pA.y; ra2 += pA.z; ra3 += pA.w;
              const float4 pB = *(const float4*)(Wpb + base + (size_t)pp * 4096 + h * 4);
              rb0 += pB.x; rb1 += pB.y; rb2 += pB.z; rb3 += pB.w;
            }
            va[h * 4 + 0] = ra0; va[h * 4 + 1] = ra1;
            va[h * 4 + 2] = ra2; va[h * 4 + 3] = ra3;
            vb[h * 4 + 0] = rb0; vb[h * 4 + 1] = rb1;
            vb[h * 4 + 2] = rb2; vb[h * 4 + 3] = rb3;
          }
        }
      } else if (st < 12) {
        const int kq = ((st < 8) ? (st - 4) : (st - 8)) * 32 + kq8;
        const float* pa = sbq2_a + ((size_t)b * 128 + l0 + al) * 128 + kq;
        const float* pb = sbq2_b + ((size_t)b * 128 + l0 + al) * 128 + kq;
#pragma unroll
        for (int h = 0; h < 2; ++h) {
          const float4 p = *(const float4*)(pa + h * 4);
          va[h * 4 + 0] = p.x; va[h * 4 + 1] = p.y; va[h * 4 + 2] = p.z; va[h * 4 + 3] = p.w;
          const float4 q = *(const float4*)(pb + h * 4);
          vb[h * 4 + 0] = q.x; vb[h * 4 + 1] = q.y; vb[h * 4 + 2] = q.z; vb[h * 4 + 3] = q.w;
        }
      } else if (akb < 2) {
        const float* pa = sbe2_a + ((size_t)b * 128 + l0 + al) * 16 + kq8;
        const float* pb = sbe2_b + ((size_t)b * 128 + l0 + al) * 16 + kq8;
#pragma unroll
        for (int h = 0; h < 2; ++h) {
          const float4 p = *(const float4*)(pa + h * 4);
          va[h * 4 + 0] = p.x; va[h * 4 + 1] = p.y; va[h * 4 + 2] = p.z; va[h * 4 + 3] = p.w;
          const float4 q = *(const float4*)(pb + h * 4);
          vb[h * 4 + 0] = q.x; vb[h * 4 + 1] = q.y; vb[h * 4 + 2] = q.z; vb[h * 4 + 3] = q.w;
        }
      }
      ushort4 u0, u1;
      u0.x = f2bf(va[0]); u0.y = f2bf(va[1]); u0.z = f2bf(va[2]); u0.w = f2bf(va[3]);
      u1.x = f2bf(va[4]); u1.y = f2bf(va[5]); u1.z = f2bf(va[6]); u1.w = f2bf(va[7]);
      *(ushort4*)&Aa[al][kq8] = u0; *(ushort4*)&Aa[al][kq8 + 4] = u1;
      u0.x = f2bf(vb[0]); u0.y = f2bf(vb[1]); u0.z = f2bf(vb[2]); u0.w = f2bf(vb[3]);
      u1.x = f2bf(vb[4]); u1.y = f2bf(vb[5]); u1.z = f2bf(vb[6]); u1.w = f2bf(vb[7]);
      *(ushort4*)&Ab[al][kq8] = u0; *(ushort4*)&Ab[al][kq8 + 4] = u1;
    }
    {
      if (st < 4) {
        const int kk = k0 + bkl;
        const unsigned short* ra = cab + ((size_t)b * 128 + kk) * 512 + d0 + bdb;
        const unsigned short* rb = cbb + ((size_t)b * 128 + kk) * 512 + d0 + bdb;
#pragma unroll
        for (int j = 0; j < 16; j += 4) {
          const ushort4 ua = *(const ushort4*)(ra + j);
          const ushort4 ub = *(const ushort4*)(rb + j);
          Ba[bdb + j + 0][bkl] = ua.x; Ba[bdb + j + 1][bkl] = ua.y;
          Ba[bdb + j + 2][bkl] = ua.z; Ba[bdb + j + 3][bkl] = ua.w;
          Bb[bdb + j + 0][bkl] = ub.x; Bb[bdb + j + 1][bkl] = ub.y;
          Bb[bdb + j + 2][bkl] = ub.z; Bb[bdb + j + 3][bkl] = ub.w;
        }
      } else if (st < 12) {
        const bool lo = (st >= 8);
        const int r = ((st < 8) ? (k0 - 128) : (k0 - 256)) + bkl;
        const unsigned short* rp = (lo ? condl : condh) + ((size_t)b * 128 + r) * 512 + d0 + bdb;
#pragma unroll
        for (int j = 0; j < 16; j += 4) {
          const ushort4 v = *(const ushort4*)(rp + j);
          Ba[bdb + j + 0][bkl] = v.x; Ba[bdb + j + 1][bkl] = v.y;
          Ba[bdb + j + 2][bkl] = v.z; Ba[bdb + j + 3][bkl] = v.w;
        }
      } else {
        if (bkl < 16) {
          const float* rp = btab + (size_t)bkl * 512 + d0 + bdb;
#pragma unroll
          for (int j = 0; j < 16; j += 4) {
            const float4 v = *(const float4*)(rp + j);
            Ba[bdb + j + 0][bkl] = f2bf(v.x); Ba[bdb + j + 1][bkl] = f2bf(v.y);
            Ba[bdb + j + 2][bkl] = f2bf(v.z); Ba[bdb + j + 3][bkl] = f2bf(v.w);
          }
        } else {
#pragma unroll
          for (int j = 0; j < 16; ++j) Ba[bdb + j][bkl] = 0;
        }
      }
    }
    __syncthreads();
    const bool shared_b = (st >= 4);
    bf16x8 afa[4], afb[4];
#pragma unroll
    for (int i = 0; i < 4; ++i) {
      afa[i] = *(const bf16x8*)&Aa[16 * i + fr][fk];
      afb[i] = *(const bf16x8*)&Ab[16 * i + fr][fk];
    }
    __builtin_amdgcn_s_setprio(1);
#pragma unroll
    for (int jj = 0; jj < 2; ++jj) {
      const bf16x8 bfa = *(const bf16x8*)&Ba[dl0 + 16 * jj + fr][fk];
      const bf16x8 bfb = shared_b ? bfa : *(const bf16x8*)&Bb[dl0 + 16 * jj + fr][fk];
#pragma unroll
      for (int i = 0; i < 4; ++i) {
        acc[i][jj][0] = __builtin_amdgcn_mfma_f32_16x16x32_bf16(afa[i], bfa, acc[i][jj][0], 0, 0, 0);
        acc[i][jj][1] = __builtin_amdgcn_mfma_f32_16x16x32_bf16(afb[i], bfb, acc[i][jj][1], 0, 0, 0);
      }
    }
    __builtin_amdgcn_s_setprio(0);
  }
  const int fq4 = (lane >> 4) * 4;
#pragma unroll
  for (int jj = 0; jj < 2; ++jj) {
    const int d = d0 + dl0 + 16 * jj + fr;
#pragma unroll
    for (int i = 0; i < 4; ++i) {
#pragma unroll
      for (int q = 0; q < 4; ++q) {
        const int lg = l0 + 16 * i + fq4 + q;
        const size_t o = ((size_t)b * 128 + lg) * 512 + d;
        const float s = bf2f(selb[o]);
        const float va = acc[i][jj][0][q], vb = acc[i][jj][1][q];
        out[o] = vb + s * (va - vb);
      }
    }
  }
}

// ---------------------------------------------------------------------------
extern "C" void kernel_launch(void* const* d_in, const int* in_sizes, int n_in,
                              void* d_out, int out_size, void* d_ws, size_t ws_size,
                              hipStream_t stream) {
  const float* x      = (const float*)d_in[0];
  // d_in[1] n_indexes (arange) and d_in[2] mask (causal tril) are structural.
  const float* cond_w = (const float*)d_in[3];
  const float* cond_b = (const float*)d_in[4];
  const float* qtab   = (const float*)d_in[5];
  const float* btab   = (const float*)d_in[6];
  const float* key_w  = (const float*)d_in[7];
  const float* key_b  = (const float*)d_in[8];
  const float* ca_w   = (const float*)d_in[9];
  const float* ca_b   = (const float*)d_in[10];
  const float* ca1_w  = (const float*)d_in[11];
  const float* ca1_b  = (const float*)d_in[12];
  const float* cb_w   = (const float*)d_in[13];
  const float* cb_b   = (const float*)d_in[14];
  const float* cb1_w  = (const float*)d_in[15];
  const float* cb1_b  = (const float*)d_in[16];
  const float* sel_w  = (const float*)d_in[17];
  const float* sel_b  = (const float*)d_in[18];
  float* out = (float*)d_out;

  // ---- workspace layout ----
  unsigned short* uA = (unsigned short*)d_ws;
  unsigned short* xh    = uA;                  // 2097152
  unsigned short* wh    = uA + 4194304;        // 7*262144 (cond,key,ca,cb,sel,ca1,cb1)
  unsigned short* wl    = uA + 6029312;
  unsigned short* tmpah = uA + 7864320;        // 2097152 each
  unsigned short* tmpbh = uA + 12058624;
  // S2: persistent across phases (7 x 4MB bf16)
  unsigned short* s2 = (unsigned short*)((char*)d_ws + 32505856);
  unsigned short* condh = s2;
  unsigned short* condl = condh + 2097152;
  unsigned short* xkeyh = condl + 2097152;
  unsigned short* xkeyl = xkeyh + 2097152;
  unsigned short* cab   = xkeyl + 2097152;
  unsigned short* cbb   = cab + 2097152;
  unsigned short* selb  = cbb + 2097152;
  // C (phase-2 floats) aliases S1: now 24.4 MB <= 32.5 MB
  float* fC = (float*)d_ws;
  float* ZR        = fC;                  // 589824
  float* inv_fw_a  = fC + 589824;
  float* inv_fw_b  = fC + 655360;
  float* invS_bw_a = fC + 720896;
  float* invS_bw_b = fC + 724992;
  float* sbq2_a    = fC + 729088;
  float* sbq2_b    = fC + 1253376;
  float* sbe2_a    = fC + 1777664;
  float* sbe2_b    = fC + 1843200;
  float* Wpa       = fC + 1908736;        // 32*16*4096 = 2097152 floats
  float* Wpb       = fC + 4005888;        // ends 6103040 f = 24.4 MB

  cvt_split<<<3840, 256, 0, stream>>>(x, cond_w, key_w, ca_w, cb_w,
                                      sel_w, ca1_w, cb1_w, xh, wh, wl);

  linA_fused<<<dim3(32, 40), 256, 0, stream>>>(
      xh, wh, wl, cond_b, key_b, ca_b, cb_b, sel_b,
      condh, condl, xkeyh, xkeyl, tmpah, tmpbh, selb);

  // merged: qtck (288 blocks) + linB (512 blocks), mutually independent
  mid_fused<<<800, 256, 0, stream>>>(qtab, condh, condl, xkeyh, xkeyl, ZR,
                                     tmpah, tmpbh, wh, wl, ca1_b, cb1_b,
                                     cab, cbb);

  sums_fused<<<2304, 256, 0, stream>>>(ZR, inv_fw_a, inv_fw_b,
                                       invS_bw_a, invS_bw_b,
                                       sbq2_a, sbq2_b, sbe2_a, sbe2_b);

  wmat_mfma<<<BS * 16, 256, 0, stream>>>(ZR, inv_fw_a, inv_fw_b,
                                         invS_bw_a, invS_bw_b, Wpa, Wpb);

  final_mfma<<<dim3(BS, 2, 4), 256, 0, stream>>>(Wpa, Wpb, sbq2_a, sbq2_b,
                                                 sbe2_a, sbe2_b, cab, cbb,
                                                 condh, condl, btab, selb, out);
}

// Round 18
// 134.537 us; speedup vs baseline: 1.0103x; 1.0103x over previous
//
#include <hip/hip_runtime.h>
#include <cstddef>
#include <cstdint>

// Problem constants (bs=32, L=128, d=512, E=16)
#define BS 32
#define LL 128
#define DD 512
#define EE 16
#define EPSF 1e-9f
#define INV_SQRT_D 0.04419417382415922f  // 1/sqrt(512)

typedef short bf16x8 __attribute__((ext_vector_type(8)));
typedef float f32x4 __attribute__((ext_vector_type(4)));

__device__ __forceinline__ float sigmoidf_(float x) {
  return 1.f / (1.f + __expf(-x));
}
__device__ __forceinline__ unsigned short f2bf(float f) {  // RNE
  union { float f; unsigned u; } v; v.f = f;
  unsigned r = v.u + 0x7fffu + ((v.u >> 16) & 1u);
  return (unsigned short)(r >> 16);
}
__device__ __forceinline__ float bf2f(unsigned short h) {
  union { unsigned u; float f; } v; v.u = ((unsigned)h) << 16; return v.f;
}

// Swizzle scheme for [R][32-ushort] LDS tiles (64B rows):
// staging source quad = (lane&3)^((lane>>3)&3); read quad = ((lane>>4)^((lane>>1)&3)).
// Verified r8: SQ_LDS_BANK_CONFLICT 3.9M -> 0.

// ---------------------------------------------------------------------------
// K0: fp32 -> bf16 staging. x: hi only (r15-validated, absmax 0.0431).
// Weights: split hi+lo (precision-critical factor).
// ---------------------------------------------------------------------------
__global__ __launch_bounds__(256) void cvt_split(
    const float* __restrict__ x,
    const float* __restrict__ w0, const float* __restrict__ w1,
    const float* __restrict__ w2, const float* __restrict__ w3,
    const float* __restrict__ w4, const float* __restrict__ w5,
    const float* __restrict__ w6,
    unsigned short* __restrict__ xh,
    unsigned short* __restrict__ wh, unsigned short* __restrict__ wl)
{
  const int q = blockIdx.x * 256 + threadIdx.x;   // quad index
  if (q >= 983040) return;
  if (q < 524288) {
    const float4 v = *(const float4*)(x + (size_t)q * 4);
    ushort4 h;
    h.x = f2bf(v.x); h.y = f2bf(v.y); h.z = f2bf(v.z); h.w = f2bf(v.w);
    *(ushort4*)(xh + (size_t)q * 4) = h;
    return;
  }
  const int qq = q - 524288;
  const int seg = qq >> 16;
  const int off = (qq & 65535) * 4;
  const float* p;
  if      (seg == 0) p = w0; else if (seg == 1) p = w1;
  else if (seg == 2) p = w2; else if (seg == 3) p = w3;
  else if (seg == 4) p = w4; else if (seg == 5) p = w5;
  else               p = w6;
  const float4 v = *(const float4*)(p + off);
  ushort4 h, l;
  h.x = f2bf(v.x); l.x = f2bf(v.x - bf2f(h.x));
  h.y = f2bf(v.y); l.y = f2bf(v.y - bf2f(h.y));
  h.z = f2bf(v.z); l.z = f2bf(v.z - bf2f(h.z));
  h.w = f2bf(v.w); l.w = f2bf(v.w - bf2f(h.w));
  *(ushort4*)(wh + (size_t)qq * 4) = h;
  *(ushort4*)(wl + (size_t)qq * 4) = l;
}

// ---------------------------------------------------------------------------
// K1: fused 5-way MFMA linear over x (validated r15/r16): N=2560.
// ---------------------------------------------------------------------------
__global__ __launch_bounds__(256) void linA_fused(
    const unsigned short* __restrict__ xh,
    const unsigned short* __restrict__ wh, const unsigned short* __restrict__ wl,
    const float* __restrict__ b0, const float* __restrict__ b1,
    const float* __restrict__ b2, const float* __restrict__ b3,
    const float* __restrict__ b4,
    unsigned short* __restrict__ condh, unsigned short* __restrict__ condl,
    unsigned short* __restrict__ xkeyh, unsigned short* __restrict__ xkeyl,
    unsigned short* __restrict__ tmpah, unsigned short* __restrict__ tmpbh,
    unsigned short* __restrict__ selb)
{
  __shared__ __align__(16) char smem[32768];   // 2 x 16KB buffers
  const int tid = threadIdx.x;
  const int wv = tid >> 6, lane = tid & 63;
  const int m0 = blockIdx.x * 128;
  const int nglob0 = blockIdx.y * 64;
  const int seg = nglob0 >> 9;               // 0..4
  const int n0 = nglob0 & 511;
  const unsigned short* Wh = wh + (size_t)seg * 262144;
  const unsigned short* Wl = wl + (size_t)seg * 262144;
  const float* bias = (seg == 0) ? b0 : (seg == 1) ? b1 : (seg == 2) ? b2
                      : (seg == 3) ? b3 : b4;
  const int wm = (wv >> 1) * 64, wn = (wv & 1) * 32;
  const int sr4 = lane >> 2;
  const int scol = ((lane & 3) ^ ((lane >> 3) & 3)) * 8;
  const int fr = lane & 15;
  const int fk = (((lane >> 4) ^ ((lane >> 1) & 3))) * 8;

  auto stage = [&](int d, int k0) {
    char* base = smem + d * 16384;
    unsigned short* AsH = (unsigned short*)base;            // 8KB (128x32)
    unsigned short* BsH = (unsigned short*)(base + 8192);   // 4KB (64x32)
    unsigned short* BsL = (unsigned short*)(base + 12288);  // 4KB
#pragma unroll
    for (int c = 0; c < 2; ++c) {
      const size_t ga = (size_t)(m0 + wv * 32 + c * 16 + sr4) * 512 + k0 + scol;
      __builtin_amdgcn_global_load_lds(
          (const __attribute__((address_space(1))) unsigned int*)(xh + ga),
          (__attribute__((address_space(3))) unsigned int*)(AsH + wv * 1024 + c * 512),
          16, 0, 0);
    }
    {
      const size_t gb = (size_t)(n0 + wv * 16 + sr4) * 512 + k0 + scol;
      __builtin_amdgcn_global_load_lds(
          (const __attribute__((address_space(1))) unsigned int*)(Wh + gb),
          (__attribute__((address_space(3))) unsigned int*)(BsH + wv * 512),
          16, 0, 0);
      __builtin_amdgcn_global_load_lds(
          (const __attribute__((address_space(1))) unsigned int*)(Wl + gb),
          (__attribute__((address_space(3))) unsigned int*)(BsL + wv * 512),
          16, 0, 0);
    }
  };

  f32x4 acc[4][2] = {};
  stage(0, 0);
  __syncthreads();
  for (int k0 = 0; k0 < 512; k0 += 32) {
    const int cur = (k0 >> 5) & 1;
    if (k0 + 32 < 512) stage(cur ^ 1, k0 + 32);
    char* base = smem + cur * 16384;
    unsigned short* AsH = (unsigned short*)base;
    unsigned short* BsH = (unsigned short*)(base + 8192);
    unsigned short* BsL = (unsigned short*)(base + 12288);
    bf16x8 ah[4], bh[2], bl[2];
#pragma unroll
    for (int i = 0; i < 4; ++i)
      ah[i] = *(const bf16x8*)&AsH[(wm + 16 * i + fr) * 32 + fk];
#pragma unroll
    for (int j = 0; j < 2; ++j) {
      bh[j] = *(const bf16x8*)&BsH[(wn + 16 * j + fr) * 32 + fk];
      bl[j] = *(const bf16x8*)&BsL[(wn + 16 * j + fr) * 32 + fk];
    }
    __builtin_amdgcn_s_setprio(1);
#pragma unroll
    for (int i = 0; i < 4; ++i)
#pragma unroll
      for (int j = 0; j < 2; ++j) {
        acc[i][j] = __builtin_amdgcn_mfma_f32_16x16x32_bf16(ah[i], bh[j], acc[i][j], 0, 0, 0);
        acc[i][j] = __builtin_amdgcn_mfma_f32_16x16x32_bf16(ah[i], bl[j], acc[i][j], 0, 0, 0);
      }
    __builtin_amdgcn_s_setprio(0);
    __syncthreads();
  }
  // ---- vectorized epilogue via LDS transpose (2 passes of 64 rows) ----
  const int fq4 = (lane >> 4) * 4;
  float (*Epi)[68] = (float(*)[68])smem;
  const int ep_row = tid >> 2;          // 0..63
  const int ep_c0 = (tid & 3) * 16;     // 0,16,32,48
  for (int pass = 0; pass < 2; ++pass) {
    __syncthreads();
    if ((wv >> 1) == pass) {
#pragma unroll
      for (int j = 0; j < 2; ++j)
#pragma unroll
        for (int i = 0; i < 4; ++i)
#pragma unroll
          for (int q = 0; q < 4; ++q)
            Epi[16 * i + fq4 + q][wn + 16 * j + fr] = acc[i][j][q];
    }
    __syncthreads();
    const int m = m0 + pass * 64 + ep_row;
    const int nb = n0 + ep_c0;
    float vv[16];
#pragma unroll
    for (int t = 0; t < 4; ++t) {
      const float4 e = *(const float4*)&Epi[ep_row][ep_c0 + 4 * t];
      const float4 bv = *(const float4*)(bias + nb + 4 * t);
      vv[4 * t + 0] = e.x + bv.x; vv[4 * t + 1] = e.y + bv.y;
      vv[4 * t + 2] = e.z + bv.z; vv[4 * t + 3] = e.w + bv.w;
    }
    const size_t o = (size_t)m * 512 + nb;
    if (seg <= 1) {
      unsigned hu[8], lu[8];
#pragma unroll
      for (int t = 0; t < 8; ++t) {
        const float v0 = vv[2 * t], v1 = vv[2 * t + 1];
        const unsigned short h0 = f2bf(v0), h1 = f2bf(v1);
        hu[t] = (unsigned)h0 | ((unsigned)h1 << 16);
        lu[t] = (unsigned)f2bf(v0 - bf2f(h0)) | ((unsigned)f2bf(v1 - bf2f(h1)) << 16);
      }
      unsigned short* oh = seg ? xkeyh : condh;
      unsigned short* ol = seg ? xkeyl : condl;
      uint4 H0, H1, L0, L1;
      H0.x = hu[0]; H0.y = hu[1]; H0.z = hu[2]; H0.w = hu[3];
      H1.x = hu[4]; H1.y = hu[5]; H1.z = hu[6]; H1.w = hu[7];
      L0.x = lu[0]; L0.y = lu[1]; L0.z = lu[2]; L0.w = lu[3];
      L1.x = lu[4]; L1.y = lu[5]; L1.z = lu[6]; L1.w = lu[7];
      *(uint4*)(oh + o) = H0; *(uint4*)(oh + o + 8) = H1;
      *(uint4*)(ol + o) = L0; *(uint4*)(ol + o + 8) = L1;
    } else if (seg <= 3) {
      unsigned hu[8];
#pragma unroll
      for (int t = 0; t < 8; ++t)
        hu[t] = (unsigned)f2bf(vv[2 * t]) | ((unsigned)f2bf(vv[2 * t + 1]) << 16);
      unsigned short* oh = (seg == 2) ? tmpah : tmpbh;
      uint4 H0, H1;
      H0.x = hu[0]; H0.y = hu[1]; H0.z = hu[2]; H0.w = hu[3];
      H1.x = hu[4]; H1.y = hu[5]; H1.z = hu[6]; H1.w = hu[7];
      *(uint4*)(oh + o) = H0; *(uint4*)(oh + o + 8) = H1;
    } else {
      unsigned hu[8];
#pragma unroll
      for (int t = 0; t < 8; ++t)
        hu[t] = (unsigned)f2bf(sigmoidf_(vv[2 * t]))
              | ((unsigned)f2bf(sigmoidf_(vv[2 * t + 1])) << 16);
      uint4 H0, H1;
      H0.x = hu[0]; H0.y = hu[1]; H0.z = hu[2]; H0.w = hu[3];
      H1.x = hu[4]; H1.y = hu[5]; H1.z = hu[6]; H1.w = hu[7];
      *(uint4*)(selb + o) = H0; *(uint4*)(selb + o + 8) = H1;
    }
  }
}

// ---------------------------------------------------------------------------
// K2: MERGED mid-stage (validated r16): blocks 0..287 = qtck, 288..799 = linB.
// ---------------------------------------------------------------------------
__global__ __launch_bounds__(256) void mid_fused(
    const float* __restrict__ qtab,
    const unsigned short* __restrict__ condh, const unsigned short* __restrict__ condl,
    const unsigned short* __restrict__ xkeyh, const unsigned short* __restrict__ xkeyl,
    float* __restrict__ ZR,
    const unsigned short* __restrict__ tmpah, const unsigned short* __restrict__ tmpbh,
    const unsigned short* __restrict__ wh, const unsigned short* __restrict__ wl,
    const float* __restrict__ bca1, const float* __restrict__ bcb1,
    unsigned short* __restrict__ cab, unsigned short* __restrict__ cbb)
{
  __shared__ __align__(16) char smem[32768];
  const int tid = threadIdx.x;
  const int wv = tid >> 6, lane = tid & 63;
  const int sr4 = lane >> 2;
  const int scol = ((lane & 3) ^ ((lane >> 3) & 3)) * 8;
  const int fr = lane & 15;
  const int fk = (((lane >> 4) ^ ((lane >> 1) & 3))) * 8;

  if (blockIdx.x < 288) {
    // ================= qtck path =================
    unsigned short* Ahs = (unsigned short*)smem;             // 2KB (16x32)
    unsigned short* Als = (unsigned short*)(smem + 2048);    // 2KB
    unsigned short* Bhs = (unsigned short*)(smem + 4096);    // 8KB (128x32)
    unsigned short* Bls = (unsigned short*)(smem + 12288);   // 8KB
    const int blk = blockIdx.x;
    const int b = blk / 9, mi = blk % 9;
    const unsigned short* Asrch = condh + ((size_t)b * 128 + (mi - 1) * 16) * 512;
    const unsigned short* Asrcl = condl + ((size_t)b * 128 + (mi - 1) * 16) * 512;
    f32x4 acc[2] = {};
    for (int k0 = 0; k0 < 512; k0 += 32) {
      __syncthreads();
      if (mi == 0) {
        const int idx = tid * 2;
        const int row = idx >> 5, col = idx & 31;
        const float2 v = *(const float2*)(qtab + (size_t)row * 512 + k0 + col);
        const int pos = row * 32 + (((col >> 3) ^ ((row >> 1) & 3)) * 8) + (col & 7);
        const unsigned short h0 = f2bf(v.x), h1 = f2bf(v.y);
        ushort2 hh, ll;
        hh.x = h0; hh.y = h1;
        ll.x = f2bf(v.x - bf2f(h0)); ll.y = f2bf(v.y - bf2f(h1));
        *(ushort2*)&Ahs[pos] = hh;
        *(ushort2*)&Als[pos] = ll;
      } else {
        if (wv == 0) {
          const size_t ga = (size_t)sr4 * 512 + k0 + scol;
          __builtin_amdgcn_global_load_lds(
              (const __attribute__((address_space(1))) unsigned int*)(Asrch + ga),
              (__attribute__((address_space(3))) unsigned int*)Ahs, 16, 0, 0);
        } else if (wv == 1) {
          const size_t ga = (size_t)sr4 * 512 + k0 + scol;
          __builtin_amdgcn_global_load_lds(
              (const __attribute__((address_space(1))) unsigned int*)(Asrcl + ga),
              (__attribute__((address_space(3))) unsigned int*)Als, 16, 0, 0);
        }
      }
#pragma unroll
      for (int t = 0; t < 2; ++t) {
        const int issue = wv * 2 + t;
        const size_t gb = ((size_t)b * 128 + issue * 16 + sr4) * 512 + k0 + scol;
        __builtin_amdgcn_global_load_lds(
            (const __attribute__((address_space(1))) unsigned int*)(xkeyh + gb),
            (__attribute__((address_space(3))) unsigned int*)(Bhs + issue * 512),
            16, 0, 0);
        __builtin_amdgcn_global_load_lds(
            (const __attribute__((address_space(1))) unsigned int*)(xkeyl + gb),
            (__attribute__((address_space(3))) unsigned int*)(Bls + issue * 512),
            16, 0, 0);
      }
      __syncthreads();
      const bf16x8 ah = *(const bf16x8*)&Ahs[fr * 32 + fk];
      const bf16x8 al = *(const bf16x8*)&Als[fr * 32 + fk];
      __builtin_amdgcn_s_setprio(1);
#pragma unroll
      for (int j = 0; j < 2; ++j) {
        const int nf = wv * 2 + j;
        const bf16x8 bh = *(const bf16x8*)&Bhs[(16 * nf + fr) * 32 + fk];
        const bf16x8 bl = *(const bf16x8*)&Bls[(16 * nf + fr) * 32 + fk];
        acc[j] = __builtin_amdgcn_mfma_f32_16x16x32_bf16(ah, bh, acc[j], 0, 0, 0);
        acc[j] = __builtin_amdgcn_mfma_f32_16x16x32_bf16(ah, bl, acc[j], 0, 0, 0);
        acc[j] = __builtin_amdgcn_mfma_f32_16x16x32_bf16(al, bh, acc[j], 0, 0, 0);
      }
      __builtin_amdgcn_s_setprio(0);
    }
    const int fq4 = (lane >> 4) * 4;
#pragma unroll
    for (int j = 0; j < 2; ++j) {
      const int n = 16 * (wv * 2 + j) + fr;
#pragma unroll
      for (int q = 0; q < 4; ++q) {
        const int m = mi * 16 + fq4 + q;
        ZR[((size_t)b * 144 + m) * 128 + n] = acc[j][q] * INV_SQRT_D;
      }
    }
    return;
  }

  // ================= linB path =================
  const int idx = blockIdx.x - 288;       // 0..511
  const int m0 = (idx & 31) * 128;
  const int by = idx >> 5;                // 0..15
  const int seg = by >> 3;
  const int n0 = (by & 7) * 64;
  const unsigned short* Ah = seg ? tmpbh : tmpah;
  const unsigned short* Wh = wh + (size_t)(5 + seg) * 262144;
  const unsigned short* Wl = wl + (size_t)(5 + seg) * 262144;
  const float* bias = seg ? bcb1 : bca1;
  unsigned short* out = seg ? cbb : cab;
  const int wm = (wv >> 1) * 64, wn = (wv & 1) * 32;

  auto stage = [&](int d, int k0) {
    char* base = smem + d * 16384;
    unsigned short* AsH = (unsigned short*)base;
    unsigned short* BsH = (unsigned short*)(base + 8192);
    unsigned short* BsL = (unsigned short*)(base + 12288);
#pragma unroll
    for (int c = 0; c < 2; ++c) {
      const size_t ga = (size_t)(m0 + wv * 32 + c * 16 + sr4) * 512 + k0 + scol;
      __builtin_amdgcn_global_load_lds(
          (const __attribute__((address_space(1))) unsigned int*)(Ah + ga),
          (__attribute__((address_space(3))) unsigned int*)(AsH + wv * 1024 + c * 512),
          16, 0, 0);
    }
    {
      const size_t gb = (size_t)(n0 + wv * 16 + sr4) * 512 + k0 + scol;
      __builtin_amdgcn_global_load_lds(
          (const __attribute__((address_space(1))) unsigned int*)(Wh + gb),
          (__attribute__((address_space(3))) unsigned int*)(BsH + wv * 512),
          16, 0, 0);
      __builtin_amdgcn_global_load_lds(
          (const __attribute__((address_space(1))) unsigned int*)(Wl + gb),
          (__attribute__((address_space(3))) unsigned int*)(BsL + wv * 512),
          16, 0, 0);
    }
  };

  f32x4 acc[4][2] = {};
  stage(0, 0);
  __syncthreads();
  for (int k0 = 0; k0 < 512; k0 += 32) {
    const int cur = (k0 >> 5) & 1;
    if (k0 + 32 < 512) stage(cur ^ 1, k0 + 32);
    char* base = smem + cur * 16384;
    unsigned short* AsH = (unsigned short*)base;
    unsigned short* BsH = (unsigned short*)(base + 8192);
    unsigned short* BsL = (unsigned short*)(base + 12288);
    bf16x8 ah[4], bh[2], bl[2];
#pragma unroll
    for (int i = 0; i < 4; ++i)
      ah[i] = *(const bf16x8*)&AsH[(wm + 16 * i + fr) * 32 + fk];
#pragma unroll
    for (int j = 0; j < 2; ++j) {
      bh[j] = *(const bf16x8*)&BsH[(wn + 16 * j + fr) * 32 + fk];
      bl[j] = *(const bf16x8*)&BsL[(wn + 16 * j + fr) * 32 + fk];
    }
    __builtin_amdgcn_s_setprio(1);
#pragma unroll
    for (int i = 0; i < 4; ++i)
#pragma unroll
      for (int j = 0; j < 2; ++j) {
        acc[i][j] = __builtin_amdgcn_mfma_f32_16x16x32_bf16(ah[i], bh[j], acc[i][j], 0, 0, 0);
        acc[i][j] = __builtin_amdgcn_mfma_f32_16x16x32_bf16(ah[i], bl[j], acc[i][j], 0, 0, 0);
      }
    __builtin_amdgcn_s_setprio(0);
    __syncthreads();
  }
  const int fq4 = (lane >> 4) * 4;
  float (*Epi)[68] = (float(*)[68])smem;
  const int ep_row = tid >> 2;
  const int ep_c0 = (tid & 3) * 16;
  for (int pass = 0; pass < 2; ++pass) {
    __syncthreads();
    if ((wv >> 1) == pass) {
#pragma unroll
      for (int j = 0; j < 2; ++j)
#pragma unroll
        for (int i = 0; i < 4; ++i)
#pragma unroll
          for (int q = 0; q < 4; ++q)
            Epi[16 * i + fq4 + q][wn + 16 * j + fr] = acc[i][j][q];
    }
    __syncthreads();
    const int m = m0 + pass * 64 + ep_row;
    const int nb = n0 + ep_c0;
    const size_t o = (size_t)m * 512 + nb;
    float vv[16];
#pragma unroll
    for (int t = 0; t < 4; ++t) {
      const float4 e = *(const float4*)&Epi[ep_row][ep_c0 + 4 * t];
      const float4 bv = *(const float4*)(bias + nb + 4 * t);
      vv[4 * t + 0] = e.x + bv.x; vv[4 * t + 1] = e.y + bv.y;
      vv[4 * t + 2] = e.z + bv.z; vv[4 * t + 3] = e.w + bv.w;
    }
    const uint4 G0 = *(const uint4*)(Ah + o);
    const uint4 G1 = *(const uint4*)(Ah + o + 8);
    const unsigned gw[8] = {G0.x, G0.y, G0.z, G0.w, G1.x, G1.y, G1.z, G1.w};
    unsigned hu[8];
#pragma unroll
    for (int t = 0; t < 8; ++t) {
      const float g0 = bf2f((unsigned short)(gw[t] & 0xffff));
      const float g1 = bf2f((unsigned short)(gw[t] >> 16));
      hu[t] = (unsigned)f2bf(g0 * sigmoidf_(vv[2 * t]))
            | ((unsigned)f2bf(g1 * sigmoidf_(vv[2 * t + 1])) << 16);
    }
    uint4 H0, H1;
    H0.x = hu[0]; H0.y = hu[1]; H0.z = hu[2]; H0.w = hu[3];
    H1.x = hu[4]; H1.y = hu[5]; H1.z = hu[6]; H1.w = hu[7];
    *(uint4*)(out + o) = H0; *(uint4*)(out + o + 8) = H1;
  }
}

// ---------------------------------------------------------------------------
// K4: fused forward + backward sums (validated r12-r16).
// ---------------------------------------------------------------------------
__global__ __launch_bounds__(256) void sums_fused(
    const float* __restrict__ ZR,
    float* __restrict__ inv_fw_a, float* __restrict__ inv_fw_b,
    float* __restrict__ invS_bw_a, float* __restrict__ invS_bw_b,
    float* __restrict__ sbq2_a, float* __restrict__ sbq2_b,
    float* __restrict__ sbe2_a, float* __restrict__ sbe2_b)
{
  __shared__ float se_a[2][16][129];
  __shared__ float se_b[2][16][129];
  __shared__ float red_a[2][128], red_b[2][128];
  const int blk = blockIdx.x;
  if (blk < 256) {
    const int idx = blk * 256 + threadIdx.x;   // b*2048+n
    const int b = idx >> 11, n = idx & 2047;
    const int lq = n >> 4, e = n & 15;
    const float* qrow = ZR + ((size_t)b * 144 + e) * LL;
    const float* crow = ZR + ((size_t)b * 144 + 16 + lq) * LL;
    float sa = 0.f, sb = 0.f;
    const int kend = lq + 1;
    int k = 0;
    for (; k + 4 <= kend; k += 4) {
      const float4 qv = *(const float4*)(qrow + k);
      const float4 cv = *(const float4*)(crow + k);
      float v;
      v = qv.x + cv.x; sa += fmaxf(v, 0.f); sb += fmaxf(-v, 0.f);
      v = qv.y + cv.y; sa += fmaxf(v, 0.f); sb += fmaxf(-v, 0.f);
      v = qv.z + cv.z; sa += fmaxf(v, 0.f); sb += fmaxf(-v, 0.f);
      v = qv.w + cv.w; sa += fmaxf(v, 0.f); sb += fmaxf(-v, 0.f);
    }
    for (; k < kend; ++k) {
      const float v = qrow[k] + crow[k];
      sa += fmaxf(v, 0.f);
      sb += fmaxf(-v, 0.f);
    }
    inv_fw_a[idx] = 1.f / (sa + EPSF);
    inv_fw_b[idx] = 1.f / (sb + EPSF);
    return;
  }
  // ---- backward part: bidx = (blk-256)*2 + half ----
  const int half = threadIdx.x >> 7;   // 0/1
  const int t = threadIdx.x & 127;     // l_q
  const int bidx = (blk - 256) * 2 + half;   // b*128 + l
  const int b = bidx >> 7, l = bidx & 127;
  const float* zb = ZR + (size_t)b * 144 * LL;
  float qa = 0.f, qb = 0.f;
  const float ckl = zb[(16 + t) * LL + l];
  if (t <= l) {
#pragma unroll
    for (int e = 0; e < 16; ++e) {
      const float v = zb[e * LL + l] + ckl;
      const float pa = fmaxf(v, 0.f), pb = fmaxf(-v, 0.f);
      se_a[half][e][t] = pa; se_b[half][e][t] = pb;
      qa += pa; qb += pb;
    }
  } else {
#pragma unroll
    for (int e = 0; e < 16; ++e) { se_a[half][e][t] = 0.f; se_b[half][e][t] = 0.f; }
  }
  red_a[half][t] = qa; red_b[half][t] = qb;
  __syncthreads();
  for (int off = 64; off >= 1; off >>= 1) {
    if (t < off) {
      red_a[half][t] += red_a[half][t + off];
      red_b[half][t] += red_b[half][t + off];
    }
    __syncthreads();
  }
  const float inv_a = 1.f / (red_a[half][0] + EPSF);
  const float inv_b = 1.f / (red_b[half][0] + EPSF);
  if (t == 0) { invS_bw_a[bidx] = inv_a; invS_bw_b[bidx] = inv_b; }
  sbq2_a[(size_t)bidx * LL + t] = qa * (2.f * inv_a);
  sbq2_b[(size_t)bidx * LL + t] = qb * (2.f * inv_b);
  if (t < 16) {
    float sa = 0.f, sb = 0.f;
    for (int i = 0; i < 128; ++i) { sa += se_a[half][t][i]; sb += se_b[half][t][i]; }
    sbe2_a[(size_t)bidx * EE + t] = sa * (2.f * inv_a);
    sbe2_b[(size_t)bidx * EE + t] = sb * (2.f * inv_b);
  }
}

// ---------------------------------------------------------------------------
// K6: fused masked-operand generation + bf16 MFMA, swizzled V/U tiles
// (validated r8-r16). Wpart[l,k] = invS_bw[l]*sum_n V[n,l]*U[n,k].
// ---------------------------------------------------------------------------
__global__ __launch_bounds__(256) void wmat_mfma(
    const float* __restrict__ ZR,
    const float* __restrict__ inv_fw_a, const float* __restrict__ inv_fw_b,
    const float* __restrict__ invS_bw_a, const float* __restrict__ invS_bw_b,
    float* __restrict__ Wpa, float* __restrict__ Wpb)
{
  __shared__ float QTs[16][128];
  __shared__ float CKs[32][128];
  __shared__ float IFa[512], IFb[512];
  __shared__ unsigned short VAt[64][32], VBt[64][32];
  __shared__ unsigned short UAt[64][32], UBt[64][32];
  const int blk = blockIdx.x;          // b*8 + s
  const int b = blk >> 3, s = blk & 7;
  int t, p;
  if (s < 2)      { t = 0; p = s; }
  else if (s < 6) { t = 1; p = s - 2; }
  else            { t = 2; p = s - 6; }
  const int l0 = (t > 0) ? 64 : 0;
  const int k0 = (t == 2) ? 64 : 0;
  const int lqb = ((t == 2) ? 64 : 0) + p * 32;
  const int tid = threadIdx.x, wv = tid >> 6, lane = tid & 63;
  const float* zb = ZR + (size_t)b * 144 * LL;
#pragma unroll
  for (int i = 0; i < 2; ++i) {
    const int o = (tid * 2 + i) * 4;
    *(float4*)((float*)QTs + o) = *(const float4*)(zb + o);
  }
  const float* cksrc = zb + (size_t)(16 + lqb) * LL;
#pragma unroll
  for (int i = 0; i < 4; ++i) {
    const int o = (tid * 4 + i) * 4;
    *(float4*)((float*)CKs + o) = *(const float4*)(cksrc + o);
  }
  {
    const int o = tid * 2;
    *(float2*)(IFa + o) = *(const float2*)(inv_fw_a + (size_t)b * 2048 + lqb * 16 + o);
    *(float2*)(IFb + o) = *(const float2*)(inv_fw_b + (size_t)b * 2048 + lqb * 16 + o);
  }
  const int gr = tid >> 2;
  const int nsub = (tid & 3) * 8;
  const int nsubs = ((tid & 3) ^ ((tid >> 3) & 3)) * 8;
  const int e0 = nsub & 15;
  const int lqo = nsub >> 4;
  const int fr = lane & 15;
  const int fk = (((lane >> 4) ^ ((lane >> 1) & 3))) * 8;
  const int lc = l0 + gr, kc = k0 + gr;
  const bool same_col = (l0 == k0);
  f32x4 aa[4] = {}, ab[4] = {};
  for (int it = 0; it < 16; ++it) {
    __syncthreads();
    const int lql = it * 2 + lqo;
    const int lqg = lqb + lql;
    const float ckv = CKs[lql][lc];
    const float cku = same_col ? ckv : CKs[lql][kc];
    const bool mv = (lqg <= lc);
    const bool mu = (kc <= lqg);
    unsigned short va[8], vb[8], ua[8], ub[8];
#pragma unroll
    for (int i = 0; i < 8; ++i) {
      const float zq = QTs[e0 + i][lc];
      const float z = zq + ckv;
      va[i] = f2bf(mv ? fmaxf(z, 0.f) : 0.f);
      vb[i] = f2bf(mv ? fmaxf(-z, 0.f) : 0.f);
      const float zq2 = same_col ? zq : QTs[e0 + i][kc];
      const float z2 = zq2 + cku;
      const float ia = IFa[lql * 16 + e0 + i];
      const float ib = IFb[lql * 16 + e0 + i];
      ua[i] = f2bf(mu ? fmaxf(z2, 0.f) * ia : 0.f);
      ub[i] = f2bf(mu ? fmaxf(-z2, 0.f) * ib : 0.f);
    }
    ushort4 w0, w1;
    w0.x = va[0]; w0.y = va[1]; w0.z = va[2]; w0.w = va[3];
    w1.x = va[4]; w1.y = va[5]; w1.z = va[6]; w1.w = va[7];
    *(ushort4*)&VAt[gr][nsubs] = w0; *(ushort4*)&VAt[gr][nsubs + 4] = w1;
    w0.x = vb[0]; w0.y = vb[1]; w0.z = vb[2]; w0.w = vb[3];
    w1.x = vb[4]; w1.y = vb[5]; w1.z = vb[6]; w1.w = vb[7];
    *(ushort4*)&VBt[gr][nsubs] = w0; *(ushort4*)&VBt[gr][nsubs + 4] = w1;
    w0.x = ua[0]; w0.y = ua[1]; w0.z = ua[2]; w0.w = ua[3];
    w1.x = ua[4]; w1.y = ua[5]; w1.z = ua[6]; w1.w = ua[7];
    *(ushort4*)&UAt[gr][nsubs] = w0; *(ushort4*)&UAt[gr][nsubs + 4] = w1;
    w0.x = ub[0]; w0.y = ub[1]; w0.z = ub[2]; w0.w = ub[3];
    w1.x = ub[4]; w1.y = ub[5]; w1.z = ub[6]; w1.w = ub[7];
    *(ushort4*)&UBt[gr][nsubs] = w0; *(ushort4*)&UBt[gr][nsubs + 4] = w1;
    __syncthreads();
    const bf16x8 afa = *(const bf16x8*)&VAt[16 * wv + fr][fk];
    const bf16x8 afb = *(const bf16x8*)&VBt[16 * wv + fr][fk];
    __builtin_amdgcn_s_setprio(1);
#pragma unroll
    for (int c = 0; c < 4; ++c) {
      const bf16x8 bfa = *(const bf16x8*)&UAt[16 * c + fr][fk];
      const bf16x8 bfb = *(const bf16x8*)&UBt[16 * c + fr][fk];
      aa[c] = __builtin_amdgcn_mfma_f32_16x16x32_bf16(afa, bfa, aa[c], 0, 0, 0);
      ab[c] = __builtin_amdgcn_mfma_f32_16x16x32_bf16(afb, bfb, ab[c], 0, 0, 0);
    }
    __builtin_amdgcn_s_setprio(0);
  }
  const int llb = 16 * wv + (lane >> 4) * 4;
#pragma unroll
  for (int c = 0; c < 4; ++c) {
    const int kl = 16 * c + fr;
#pragma unroll
    for (int q = 0; q < 4; ++q) {
      const int llo = llb + q;
      const int lg = l0 + llo;
      const float sa = invS_bw_a[b * LL + lg];
      const float sb = invS_bw_b[b * LL + lg];
      const size_t base = ((size_t)((b * 3 + t) * 4 + p)) * 4096 + (size_t)llo * 64 + kl;
      Wpa[base] = aa[c][q] * sa;
      Wpb[base] = ab[c][q] * sb;
    }
  }
}

// ---------------------------------------------------------------------------
// K7: final contraction as bf16 MFMA, K=416 (validated r7-r16).
// ---------------------------------------------------------------------------
__global__ __launch_bounds__(256) void final_mfma(
    const float* __restrict__ Wpa, const float* __restrict__ Wpb,
    const float* __restrict__ sbq2_a, const float* __restrict__ sbq2_b,
    const float* __restrict__ sbe2_a, const float* __restrict__ sbe2_b,
    const unsigned short* __restrict__ cab, const unsigned short* __restrict__ cbb,
    const unsigned short* __restrict__ condh, const unsigned short* __restrict__ condl,
    const float* __restrict__ btab,
    const unsigned short* __restrict__ selb, float* __restrict__ out)
{
  __shared__ unsigned short Aa[64][40], Ab[64][40];
  __shared__ unsigned short Ba[128][40], Bb[128][40];
  const int b = blockIdx.x, ls = blockIdx.y, ds = blockIdx.z;
  const int l0 = ls * 64, d0 = ds * 128;
  const int tid = threadIdx.x, wv = tid >> 6, lane = tid & 63;
  const int fr = lane & 15, fk = (lane >> 4) * 8;
  const int dl0 = wv * 32;
  const int al = tid & 63, akb = tid >> 6;
  const int bkl = tid >> 3, bdb = (tid & 7) * 16;
  f32x4 acc[4][2][2] = {};
  for (int st = 0; st < 13; ++st) {
    const int k0 = st * 32;
    __syncthreads();
    {
      float va[8] = {}, vb[8] = {};
      const int kq8 = akb * 8;
      if (st < 4) {
        if (ls == 0) {
          if (st < 2) {
            const size_t base = ((size_t)(b * 3 + 0) * 4) * 4096 + (size_t)al * 64 + st * 32 + kq8;
#pragma unroll
            for (int h = 0; h < 2; ++h) {
              const float4 p0 = *(const float4*)(Wpa + base + h * 4);
              const float4 p1 = *(const float4*)(Wpa + base + 4096 + h * 4);
              va[h * 4 + 0] = p0.x + p1.x; va[h * 4 + 1] = p0.y + p1.y;
              va[h * 4 + 2] = p0.z + p1.z; va[h * 4 + 3] = p0.w + p1.w;
              const float4 q0 = *(const float4*)(Wpb + base + h * 4);
              const float4 q1 = *(const float4*)(Wpb + base + 4096 + h * 4);
              vb[h * 4 + 0] = q0.x + q1.x; vb[h * 4 + 1] = q0.y + q1.y;
              vb[h * 4 + 2] = q0.z + q1.z; vb[h * 4 + 3] = q0.w + q1.w;
            }
          }
        } else {
          if (st < 2) {
            const size_t base = ((size_t)(b * 3 + 1) * 4) * 4096 + (size_t)al * 64 + st * 32 + kq8;
#pragma unroll
            for (int h = 0; h < 2; ++h) {
              const float4 p0 = *(const float4*)(Wpa + base + h * 4);
              const float4 p1 = *(const float4*)(Wpa + base + 4096 + h * 4);
              const float4 p2 = *(const float4*)(Wpa + base + 8192 + h * 4);
              const float4 p3 = *(const float4*)(Wpa + base + 12288 + h * 4);
              va[h * 4 + 0] = p0.x + p1.x + p2.x + p3.x;
              va[h * 4 + 1] = p0.y + p1.y + p2.y + p3.y;
              va[h * 4 + 2] = p0.z + p1.z + p2.z + p3.z;
              va[h * 4 + 3] = p0.w + p1.w + p2.w + p3.w;
              const float4 q0 = *(const float4*)(Wpb + base + h * 4);
              const float4 q1 = *(const float4*)(Wpb + base + 4096 + h * 4);
              const float4 q2 = *(const float4*)(Wpb + base + 8192 + h * 4);
              const float4 q3 = *(const float4*)(Wpb + base + 12288 + h * 4);
              vb[h * 4 + 0] = q0.x + q1.x + q2.x + q3.x;
              vb[h * 4 + 1] = q0.y + q1.y + q2.y + q3.y;
              vb[h * 4 + 2] = q0.z + q1.z + q2.z + q3.z;
              vb[h * 4 + 3] = q0.w + q1.w + q2.w + q3.w;
            }
          } else {
            const size_t base = ((size_t)(b * 3 + 2) * 4) * 4096 + (size_t)al * 64 + (st - 2) * 32 + kq8;
#pragma unroll
            for (int h = 0; h < 2; ++h) {
              const float4 p0 = *(const float4*)(Wpa + base + h * 4);
              const float4 p1 = *(const float4*)(Wpa + base + 4096 + h * 4);
              va[h * 4 + 0] = p0.x + p1.x; va[h * 4 + 1] = p0.y + p1.y;
              va[h * 4 + 2] = p0.z + p1.z; va[h * 4 + 3] = p0.w + p1.w;
              const float4 q0 = *(const float4*)(Wpb + base + h * 4);
              const float4 q1 = *(const float4*)(Wpb + base + 4096 + h * 4);
              vb[h * 4 + 0] = q0.x + q1.x; vb[h * 4 + 1] = q0.y + q1.y;
              vb[h * 4 + 2] = q0.z + q1.z; vb[h * 4 + 3] = q0.w + q1.w;
            }
          }
        }
      } else if (st < 12) {
        const int kq = ((st < 8) ? (st - 4) : (st - 8)) * 32 + kq8;
        const float* pa = sbq2_a + ((size_t)b * 128 + l0 + al) * 128 + kq;
        const float* pb = sbq2_b + ((size_t)b * 128 + l0 + al) * 128 + kq;
#pragma unroll
        for (int h = 0; h < 2; ++h) {
          const float4 p = *(const float4*)(pa + h * 4);
          va[h * 4 + 0] = p.x; va[h * 4 + 1] = p.y; va[h * 4 + 2] = p.z; va[h * 4 + 3] = p.w;
          const float4 q = *(const float4*)(pb + h * 4);
          vb[h * 4 + 0] = q.x; vb[h * 4 + 1] = q.y; vb[h * 4 + 2] = q.z; vb[h * 4 + 3] = q.w;
        }
      } else if (akb < 2) {
        const float* pa = sbe2_a + ((size_t)b * 128 + l0 + al) * 16 + kq8;
        const float* pb = sbe2_b + ((size_t)b * 128 + l0 + al) * 16 + kq8;
#pragma unroll
        for (int h = 0; h < 2; ++h) {
          const float4 p = *(const float4*)(pa + h * 4);
          va[h * 4 + 0] = p.x; va[h * 4 + 1] = p.y; va[h * 4 + 2] = p.z; va[h * 4 + 3] = p.w;
          const float4 q = *(const float4*)(pb + h * 4);
          vb[h * 4 + 0] = q.x; vb[h * 4 + 1] = q.y; vb[h * 4 + 2] = q.z; vb[h * 4 + 3] = q.w;
        }
      }
      ushort4 u0, u1;
      u0.x = f2bf(va[0]); u0.y = f2bf(va[1]); u0.z = f2bf(va[2]); u0.w = f2bf(va[3]);
      u1.x = f2bf(va[4]); u1.y = f2bf(va[5]); u1.z = f2bf(va[6]); u1.w = f2bf(va[7]);
      *(ushort4*)&Aa[al][kq8] = u0; *(ushort4*)&Aa[al][kq8 + 4] = u1;
      u0.x = f2bf(vb[0]); u0.y = f2bf(vb[1]); u0.z = f2bf(vb[2]); u0.w = f2bf(vb[3]);
      u1.x = f2bf(vb[4]); u1.y = f2bf(vb[5]); u1.z = f2bf(vb[6]); u1.w = f2bf(vb[7]);
      *(ushort4*)&Ab[al][kq8] = u0; *(ushort4*)&Ab[al][kq8 + 4] = u1;
    }
    {
      if (st < 4) {
        const int kk = k0 + bkl;
        const unsigned short* ra = cab + ((size_t)b * 128 + kk) * 512 + d0 + bdb;
        const unsigned short* rb = cbb + ((size_t)b * 128 + kk) * 512 + d0 + bdb;
#pragma unroll
        for (int j = 0; j < 16; j += 4) {
          const ushort4 ua = *(const ushort4*)(ra + j);
          const ushort4 ub = *(const ushort4*)(rb + j);
          Ba[bdb + j + 0][bkl] = ua.x; Ba[bdb + j + 1][bkl] = ua.y;
          Ba[bdb + j + 2][bkl] = ua.z; Ba[bdb + j + 3][bkl] = ua.w;
          Bb[bdb + j + 0][bkl] = ub.x; Bb[bdb + j + 1][bkl] = ub.y;
          Bb[bdb + j + 2][bkl] = ub.z; Bb[bdb + j + 3][bkl] = ub.w;
        }
      } else if (st < 12) {
        const bool lo = (st >= 8);
        const int r = ((st < 8) ? (k0 - 128) : (k0 - 256)) + bkl;
        const unsigned short* rp = (lo ? condl : condh) + ((size_t)b * 128 + r) * 512 + d0 + bdb;
#pragma unroll
        for (int j = 0; j < 16; j += 4) {
          const ushort4 v = *(const ushort4*)(rp + j);
          Ba[bdb + j + 0][bkl] = v.x; Ba[bdb + j + 1][bkl] = v.y;
          Ba[bdb + j + 2][bkl] = v.z; Ba[bdb + j + 3][bkl] = v.w;
        }
      } else {
        if (bkl < 16) {
          const float* rp = btab + (size_t)bkl * 512 + d0 + bdb;
#pragma unroll
          for (int j = 0; j < 16; j += 4) {
            const float4 v = *(const float4*)(rp + j);
            Ba[bdb + j + 0][bkl] = f2bf(v.x); Ba[bdb + j + 1][bkl] = f2bf(v.y);
            Ba[bdb + j + 2][bkl] = f2bf(v.z); Ba[bdb + j + 3][bkl] = f2bf(v.w);
          }
        } else {
#pragma unroll
          for (int j = 0; j < 16; ++j) Ba[bdb + j][bkl] = 0;
        }
      }
    }
    __syncthreads();
    const bool shared_b = (st >= 4);
    bf16x8 afa[4], afb[4];
#pragma unroll
    for (int i = 0; i < 4; ++i) {
      afa[i] = *(const bf16x8*)&Aa[16 * i + fr][fk];
      afb[i] = *(const bf16x8*)&Ab[16 * i + fr][fk];
    }
    __builtin_amdgcn_s_setprio(1);
#pragma unroll
    for (int jj = 0; jj < 2; ++jj) {
      const bf16x8 bfa = *(const bf16x8*)&Ba[dl0 + 16 * jj + fr][fk];
      const bf16x8 bfb = shared_b ? bfa : *(const bf16x8*)&Bb[dl0 + 16 * jj + fr][fk];
#pragma unroll
      for (int i = 0; i < 4; ++i) {
        acc[i][jj][0] = __builtin_amdgcn_mfma_f32_16x16x32_bf16(afa[i], bfa, acc[i][jj][0], 0, 0, 0);
        acc[i][jj][1] = __builtin_amdgcn_mfma_f32_16x16x32_bf16(afb[i], bfb, acc[i][jj][1], 0, 0, 0);
      }
    }
    __builtin_amdgcn_s_setprio(0);
  }
  const int fq4 = (lane >> 4) * 4;
#pragma unroll
  for (int jj = 0; jj < 2; ++jj) {
    const int d = d0 + dl0 + 16 * jj + fr;
#pragma unroll
    for (int i = 0; i < 4; ++i) {
#pragma unroll
      for (int q = 0; q < 4; ++q) {
        const int lg = l0 + 16 * i + fq4 + q;
        const size_t o = ((size_t)b * 128 + lg) * 512 + d;
        const float s = bf2f(selb[o]);
        const float va = acc[i][jj][0][q], vb = acc[i][jj][1][q];
        out[o] = vb + s * (va - vb);
      }
    }
  }
}

// ---------------------------------------------------------------------------
extern "C" void kernel_launch(void* const* d_in, const int* in_sizes, int n_in,
                              void* d_out, int out_size, void* d_ws, size_t ws_size,
                              hipStream_t stream) {
  const float* x      = (const float*)d_in[0];
  // d_in[1] n_indexes (arange) and d_in[2] mask (causal tril) are structural.
  const float* cond_w = (const float*)d_in[3];
  const float* cond_b = (const float*)d_in[4];
  const float* qtab   = (const float*)d_in[5];
  const float* btab   = (const float*)d_in[6];
  const float* key_w  = (const float*)d_in[7];
  const float* key_b  = (const float*)d_in[8];
  const float* ca_w   = (const float*)d_in[9];
  const float* ca_b   = (const float*)d_in[10];
  const float* ca1_w  = (const float*)d_in[11];
  const float* ca1_b  = (const float*)d_in[12];
  const float* cb_w   = (const float*)d_in[13];
  const float* cb_b   = (const float*)d_in[14];
  const float* cb1_w  = (const float*)d_in[15];
  const float* cb1_b  = (const float*)d_in[16];
  const float* sel_w  = (const float*)d_in[17];
  const float* sel_b  = (const float*)d_in[18];
  float* out = (float*)d_out;

  // ---- workspace layout (identical to validated r16) ----
  unsigned short* uA = (unsigned short*)d_ws;
  unsigned short* xh    = uA;                  // 2097152
  unsigned short* wh    = uA + 4194304;        // 7*262144 (cond,key,ca,cb,sel,ca1,cb1)
  unsigned short* wl    = uA + 6029312;
  unsigned short* tmpah = uA + 7864320;        // 2097152 each
  unsigned short* tmpbh = uA + 12058624;
  // S2: persistent across phases (7 x 4MB bf16)
  unsigned short* s2 = (unsigned short*)((char*)d_ws + 32505856);
  unsigned short* condh = s2;
  unsigned short* condl = condh + 2097152;
  unsigned short* xkeyh = condl + 2097152;
  unsigned short* xkeyl = xkeyh + 2097152;
  unsigned short* cab   = xkeyl + 2097152;
  unsigned short* cbb   = cab + 2097152;
  unsigned short* selb  = cbb + 2097152;
  // C (phase-2 floats) aliases S1
  float* fC = (float*)d_ws;
  float* ZR        = fC;                  // 589824
  float* inv_fw_a  = fC + 589824;
  float* inv_fw_b  = fC + 655360;
  float* invS_bw_a = fC + 720896;
  float* invS_bw_b = fC + 724992;
  float* sbq2_a    = fC + 729088;
  float* sbq2_b    = fC + 1253376;
  float* sbe2_a    = fC + 1777664;
  float* sbe2_b    = fC + 1843200;
  float* Wpa       = fC + 1908736;
  float* Wpb       = fC + 3481600;

  cvt_split<<<3840, 256, 0, stream>>>(x, cond_w, key_w, ca_w, cb_w,
                                      sel_w, ca1_w, cb1_w, xh, wh, wl);

  linA_fused<<<dim3(32, 40), 256, 0, stream>>>(
      xh, wh, wl, cond_b, key_b, ca_b, cb_b, sel_b,
      condh, condl, xkeyh, xkeyl, tmpah, tmpbh, selb);

  // merged: qtck (288 blocks) + linB (512 blocks), mutually independent
  mid_fused<<<800, 256, 0, stream>>>(qtab, condh, condl, xkeyh, xkeyl, ZR,
                                     tmpah, tmpbh, wh, wl, ca1_b, cb1_b,
                                     cab, cbb);

  sums_fused<<<2304, 256, 0, stream>>>(ZR, inv_fw_a, inv_fw_b,
                                       invS_bw_a, invS_bw_b,
                                       sbq2_a, sbq2_b, sbe2_a, sbe2_b);

  wmat_mfma<<<BS * 8, 256, 0, stream>>>(ZR, inv_fw_a, inv_fw_b,
                                        invS_bw_a, invS_bw_b, Wpa, Wpb);

  final_mfma<<<dim3(BS, 2, 4), 256, 0, stream>>>(Wpa, Wpb, sbq2_a, sbq2_b,
                                                 sbe2_a, sbe2_b, cab, cbb,
                                                 condh, condl, btab, selb, out);
}